// Round 2
// baseline (1786.584 us; speedup 1.0000x reference)
//
#include <hip/hip_runtime.h>
#include <hip/hip_bf16.h>
#include <math.h>

using bf16 = __hip_bfloat16;

// Problem constants
constexpr int kB   = 2;
constexpr int kL   = 1024;
constexpr int kD   = 512;    // d_model
constexpr int kDI  = 1024;   // inner dim
constexpr int kNS  = 16;     // d_state
constexpr int kDTR = 32;     // dt_rank
constexpr int kKC  = 4;      // conv width
constexpr int kNC  = 8;      // clusters
constexpr int kM   = kB * kL;  // 2048 rows
constexpr int kCH  = 32;       // scan chunks
constexpr int kCL  = kL / kCH; // 32 steps per chunk
constexpr float kEPS = 1e-5f;

static __device__ __forceinline__ float toF(bf16 x) { return __bfloat162float(x); }

// flag-dispatched input load: flag=1 -> fp32, flag=0 -> bf16
static __device__ __forceinline__ float ldin(const void* p, int i, int f32) {
    if (f32) return ((const float*)p)[i];
    return toF(((const bf16*)p)[i]);
}

// ---------------- dtype probe ----------------
// bf16 data: both u16 halves of each word are plausible bf16 (exponent near 127).
// fp32 data: low halves are mantissa garbage (uniform exponent field).
__global__ void detect_kernel(const unsigned short* __restrict__ x, int* __restrict__ flag) {
    if (threadIdx.x == 0 && blockIdx.x == 0) {
        int plausible = 0;
        for (int i = 0; i < 512; ++i) {
            unsigned short h = x[2 * i];  // even (low) halves
            int e = (h >> 7) & 0xFF;
            if (e >= 100 && e <= 140) plausible++;
        }
        *flag = (plausible >= 256) ? 0 : 1;  // 0 = bf16, 1 = f32
    }
}

// ---------------- block reduce (256 threads = 4 waves) ----------------
static __device__ __forceinline__ float blockReduceSum(float v, float* s) {
    __syncthreads();
#pragma unroll
    for (int o = 32; o > 0; o >>= 1) v += __shfl_down(v, o, 64);
    int lane = threadIdx.x & 63, wid = threadIdx.x >> 6;
    if (lane == 0) s[wid] = v;
    __syncthreads();
    if (threadIdx.x == 0) {
        float t = 0.f;
        for (int i = 0; i < 4; ++i) t += s[i];
        s[4] = t;
    }
    __syncthreads();
    return s[4];
}

// ---------------- LayerNorm on raw input: one block per row of 512 ----------------
__global__ __launch_bounds__(256) void ln_in_kernel(const void* __restrict__ X,
                                                    const void* __restrict__ g,
                                                    const void* __restrict__ b,
                                                    float* __restrict__ Y,
                                                    const int* __restrict__ flg) {
    __shared__ float sred[8];
    int f32 = *flg;
    int row = blockIdx.x;
    int i = threadIdx.x;
    size_t base = (size_t)row * kD;
    float x0 = ldin(X, base + i, f32), x1 = ldin(X, base + i + 256, f32);
    float mean = blockReduceSum(x0 + x1, sred) * (1.f / kD);
    float vs = blockReduceSum(x0 * x0 + x1 * x1, sred) * (1.f / kD) - mean * mean;
    float rstd = rsqrtf(vs + kEPS);
    float* yr = Y + base;
    yr[i]       = (x0 - mean) * rstd * ldin(g, i, f32)       + ldin(b, i, f32);
    yr[i + 256] = (x1 - mean) * rstd * ldin(g, i + 256, f32) + ldin(b, i + 256, f32);
}

// ---------------- LayerNorm on fp32 ws buffer ----------------
__global__ __launch_bounds__(256) void ln_f32_kernel(const float* __restrict__ X,
                                                     const void* __restrict__ g,
                                                     const void* __restrict__ b,
                                                     float* __restrict__ Y,
                                                     const int* __restrict__ flg) {
    __shared__ float sred[8];
    int f32 = *flg;
    int row = blockIdx.x;
    int i = threadIdx.x;
    size_t base = (size_t)row * kD;
    float x0 = X[base + i], x1 = X[base + i + 256];
    float mean = blockReduceSum(x0 + x1, sred) * (1.f / kD);
    float vs = blockReduceSum(x0 * x0 + x1 * x1, sred) * (1.f / kD) - mean * mean;
    float rstd = rsqrtf(vs + kEPS);
    float* yr = Y + base;
    yr[i]       = (x0 - mean) * rstd * ldin(g, i, f32)       + ldin(b, i, f32);
    yr[i + 256] = (x1 - mean) * rstd * ldin(g, i + 256, f32) + ldin(b, i + 256, f32);
}

// ---------------- generic GEMM: out = act(A[M,K] @ W[N,K]^T + bias) (+resid) ----------------
// A fp32 (lda); W/bias raw input (flag dtype). act: 0 none, 1 softplus, 2 gelu.
// aflip: read A rows L-flipped within each batch. oflip: write out rows L-flipped.
__global__ __launch_bounds__(256) void gemm_kernel(const float* __restrict__ A, int lda,
                                                   const void* __restrict__ W,
                                                   const void* __restrict__ bias,
                                                   int M, int N, int K, int act,
                                                   const float* __restrict__ resid,
                                                   float* __restrict__ outF,
                                                   void* __restrict__ outAny,
                                                   int ldo, int aflip, int oflip,
                                                   const int* __restrict__ flg) {
    __shared__ float As[16][64];
    __shared__ float Ws[16][64];
    int f32 = *flg;
    int tx = threadIdx.x & 15, ty = threadIdx.x >> 4;
    int m0 = blockIdx.y * 64, n0 = blockIdx.x * 64;
    float acc[4][4];
#pragma unroll
    for (int i = 0; i < 4; ++i)
#pragma unroll
        for (int j = 0; j < 4; ++j) acc[i][j] = 0.f;

    for (int kt = 0; kt < K; kt += 16) {
        for (int e = threadIdx.x; e < 1024; e += 256) {
            int m = e >> 4, kk = e & 15;
            int mr = m0 + m;
            if (aflip) mr = (mr & ~(kL - 1)) | (kL - 1 - (mr & (kL - 1)));
            As[kk][m] = A[(size_t)mr * lda + kt + kk];
        }
        for (int e = threadIdx.x; e < 1024; e += 256) {
            int n = e >> 4, kk = e & 15;
            Ws[kk][n] = ldin(W, (size_t)(n0 + n) * K + kt + kk, f32);
        }
        __syncthreads();
#pragma unroll 4
        for (int kk = 0; kk < 16; ++kk) {
            const float4 av = *reinterpret_cast<const float4*>(&As[kk][ty * 4]);
            const float4 bv = *reinterpret_cast<const float4*>(&Ws[kk][tx * 4]);
            float a_[4] = {av.x, av.y, av.z, av.w};
            float b_[4] = {bv.x, bv.y, bv.z, bv.w};
#pragma unroll
            for (int i = 0; i < 4; ++i)
#pragma unroll
                for (int j = 0; j < 4; ++j) acc[i][j] += a_[i] * b_[j];
        }
        __syncthreads();
    }

#pragma unroll
    for (int i = 0; i < 4; ++i) {
        int m = m0 + ty * 4 + i;
        int mr = m;
        if (oflip) mr = (m & ~(kL - 1)) | (kL - 1 - (m & (kL - 1)));
#pragma unroll
        for (int j = 0; j < 4; ++j) {
            int n = n0 + tx * 4 + j;
            float v = acc[i][j];
            if (bias) v += ldin(bias, n, f32);
            if (act == 1) v = (v > 20.f) ? v : log1pf(__expf(v));
            else if (act == 2) v = 0.5f * v * (1.f + erff(v * 0.70710678118654752440f));
            if (resid) v += resid[(size_t)m * ldo + n];
            size_t oi = (size_t)mr * ldo + n;
            if (outF) outF[oi] = v;
            else if (f32) ((float*)outAny)[oi] = v;
            else ((bf16*)outAny)[oi] = __float2bfloat16(v);
        }
    }
}

// ---------------- depthwise causal conv + silu ----------------
__global__ __launch_bounds__(256) void conv_kernel(const float* __restrict__ xz,
                                                   const void* __restrict__ cw,
                                                   const void* __restrict__ cb,
                                                   float* __restrict__ xc,
                                                   const int* __restrict__ flg) {
    int f32 = *flg;
    int tid = blockIdx.x * 256 + threadIdx.x;  // over kM*kDI
    int d = tid & (kDI - 1);
    int r = tid >> 10;
    int l = r & (kL - 1);
    int b = r >> 10;
    float acc = ldin(cb, d, f32);
#pragma unroll
    for (int k = 0; k < kKC; ++k) {
        int ll = l - (kKC - 1) + k;
        if (ll >= 0) acc += ldin(cw, d * kKC + k, f32) * xz[((size_t)(b * kL + ll)) * (2 * kDI) + d];
    }
    xc[(size_t)r * kDI + d] = acc / (1.f + __expf(-acc));
}

// ---------------- chunked selective scan ----------------
__global__ __launch_bounds__(256) void scan_phase1(const float* __restrict__ deltaF,
                                                   const float* __restrict__ xcF,
                                                   const float* __restrict__ xdbl,
                                                   const void* __restrict__ A_log,
                                                   float* __restrict__ PA,
                                                   float* __restrict__ HL,
                                                   const int* __restrict__ flg) {
    int f32 = *flg;
    int tid = blockIdx.x * 256 + threadIdx.x;  // B*CH*DI = 65536
    int d = tid & (kDI - 1);
    int rem = tid >> 10;
    int c = rem & (kCH - 1);
    int b = rem >> 5;
    float an[kNS], h[kNS], pa[kNS];
#pragma unroll
    for (int n = 0; n < kNS; ++n) {
        an[n] = -__expf(ldin(A_log, d * kNS + n, f32));
        h[n] = 0.f;
        pa[n] = 1.f;
    }
    int l0 = c * kCL;
    for (int l = l0; l < l0 + kCL; ++l) {
        size_t rb = (size_t)(b * kL + l);
        float dl = deltaF[rb * kDI + d];
        float xcv = xcF[rb * kDI + d];
        float du = dl * xcv;
        const float* Bp = xdbl + rb * 64 + kDTR;
#pragma unroll
        for (int n = 0; n < kNS; ++n) {
            float a = __expf(dl * an[n]);
            pa[n] *= a;
            h[n] = a * h[n] + du * Bp[n];
        }
    }
    size_t o = (((size_t)(b * kDI + d)) * kCH + c) * kNS;
#pragma unroll
    for (int n = 0; n < kNS; ++n) { PA[o + n] = pa[n]; HL[o + n] = h[n]; }
}

__global__ __launch_bounds__(256) void scan_phase2(const float* __restrict__ PA,
                                                   const float* __restrict__ HL,
                                                   float* __restrict__ HIN) {
    int tid = blockIdx.x * 256 + threadIdx.x;  // B*DI*NS = 32768
    int n = tid & (kNS - 1);
    int d = (tid >> 4) & (kDI - 1);
    int b = tid >> 14;
    float h = 0.f;
    size_t base = ((size_t)(b * kDI + d)) * kCH * kNS + n;
    for (int c = 0; c < kCH; ++c) {
        size_t idx = base + (size_t)c * kNS;
        HIN[idx] = h;
        h = PA[idx] * h + HL[idx];
    }
}

__global__ __launch_bounds__(256) void scan_phase3(const float* __restrict__ deltaF,
                                                   const float* __restrict__ xcF,
                                                   const float* __restrict__ xdbl,
                                                   const void* __restrict__ A_log,
                                                   const void* __restrict__ Dp,
                                                   const float* __restrict__ HIN,
                                                   const float* __restrict__ xz,
                                                   float* __restrict__ ymul,
                                                   const int* __restrict__ flg) {
    int f32 = *flg;
    int tid = blockIdx.x * 256 + threadIdx.x;
    int d = tid & (kDI - 1);
    int rem = tid >> 10;
    int c = rem & (kCH - 1);
    int b = rem >> 5;
    float an[kNS], h[kNS];
    size_t o = (((size_t)(b * kDI + d)) * kCH + c) * kNS;
#pragma unroll
    for (int n = 0; n < kNS; ++n) {
        an[n] = -__expf(ldin(A_log, d * kNS + n, f32));
        h[n] = HIN[o + n];
    }
    float Dv = ldin(Dp, d, f32);
    int l0 = c * kCL;
    for (int l = l0; l < l0 + kCL; ++l) {
        size_t rb = (size_t)(b * kL + l);
        float dl = deltaF[rb * kDI + d];
        float xcv = xcF[rb * kDI + d];
        float du = dl * xcv;
        const float* Bp = xdbl + rb * 64 + kDTR;
        const float* Cp = xdbl + rb * 64 + kDTR + kNS;
        float y = 0.f;
#pragma unroll
        for (int n = 0; n < kNS; ++n) {
            float a = __expf(dl * an[n]);
            h[n] = a * h[n] + du * Bp[n];
            y += h[n] * Cp[n];
        }
        y += xcv * Dv;
        float zv = xz[rb * (2 * kDI) + kDI + d];
        float sz = zv / (1.f + __expf(-zv));
        ymul[rb * kDI + d] = y * sz;
    }
}

// ---------------- cluster-center norms ----------------
__global__ void cnorm_kernel(const void* __restrict__ C, float* __restrict__ cn,
                             const int* __restrict__ flg) {
    int f32 = *flg;
    int c = blockIdx.x;
    int lane = threadIdx.x;  // 64 threads
    float s = 0.f;
    for (int i = lane; i < kD; i += 64) {
        float v = ldin(C, c * kD + i, f32);
        s += v * v;
    }
#pragma unroll
    for (int o = 32; o > 0; o >>= 1) s += __shfl_down(s, o, 64);
    if (lane == 0) cn[c] = sqrtf(s);
}

// ---------------- context clustering: sim -> softmax -> ctx -> LN ----------------
__global__ __launch_bounds__(256) void cc_kernel(const float* __restrict__ proj,
                                                 const void* __restrict__ centers,
                                                 const float* __restrict__ cn,
                                                 const float* __restrict__ xn,
                                                 const void* __restrict__ alpha_p,
                                                 const void* __restrict__ g,
                                                 const void* __restrict__ bb,
                                                 float* __restrict__ ccout,
                                                 const int* __restrict__ flg) {
    __shared__ float sred[8];
    __shared__ float sims[kNC];
    int f32 = *flg;
    int row = blockIdx.x;
    int i = threadIdx.x;
    const float* pr = proj + (size_t)row * kD;
    float p0 = pr[i], p1 = pr[i + 256];
    float sumsq = blockReduceSum(p0 * p0 + p1 * p1, sred);
    float pn = fmaxf(sqrtf(sumsq), 1e-12f);
    for (int c = 0; c < kNC; ++c) {
        float part = p0 * ldin(centers, c * kD + i, f32) + p1 * ldin(centers, c * kD + i + 256, f32);
        float dot = blockReduceSum(part, sred);
        if (threadIdx.x == 0) sims[c] = dot / (pn * fmaxf(cn[c], 1e-12f));
    }
    __syncthreads();
    float mx = -1e30f;
#pragma unroll
    for (int c = 0; c < kNC; ++c) mx = fmaxf(mx, sims[c]);
    float w[kNC], se = 0.f;
#pragma unroll
    for (int c = 0; c < kNC; ++c) { w[c] = __expf(sims[c] - mx); se += w[c]; }
    float inv = 1.f / se;
    float ctx0 = 0.f, ctx1 = 0.f;
#pragma unroll
    for (int c = 0; c < kNC; ++c) {
        float wc = w[c] * inv;
        ctx0 += wc * ldin(centers, c * kD + i, f32);
        ctx1 += wc * ldin(centers, c * kD + i + 256, f32);
    }
    float alpha = ldin(alpha_p, 0, f32);
    const float* xr = xn + (size_t)row * kD;
    float t0 = xr[i] + alpha * ctx0;
    float t1 = xr[i + 256] + alpha * ctx1;
    float mean = blockReduceSum(t0 + t1, sred) * (1.f / kD);
    float vs = blockReduceSum(t0 * t0 + t1 * t1, sred) * (1.f / kD) - mean * mean;
    float rstd = rsqrtf(vs + kEPS);
    float* yr = ccout + (size_t)row * kD;
    yr[i]       = (t0 - mean) * rstd * ldin(g, i, f32)       + ldin(bb, i, f32);
    yr[i + 256] = (t1 - mean) * rstd * ldin(g, i + 256, f32) + ldin(bb, i + 256, f32);
}

// ---------------- gated fusion + residual ----------------
__global__ __launch_bounds__(256) void gate_kernel(const float* __restrict__ xn,
                                                   const void* __restrict__ X,
                                                   const float* __restrict__ mo,
                                                   const float* __restrict__ cc,
                                                   const void* __restrict__ gw,
                                                   const void* __restrict__ gb,
                                                   float* __restrict__ xmid,
                                                   const int* __restrict__ flg) {
    __shared__ float sred[8];
    int f32 = *flg;
    int row = blockIdx.x;
    int i = threadIdx.x;
    const float* xr = xn + (size_t)row * kD;
    float x0 = xr[i], x1 = xr[i + 256];
    float d0 = blockReduceSum(x0 * ldin(gw, i, f32) + x1 * ldin(gw, i + 256, f32), sred);
    float d1 = blockReduceSum(x0 * ldin(gw, kD + i, f32) + x1 * ldin(gw, kD + i + 256, f32), sred);
    d0 += ldin(gb, 0, f32);
    d1 += ldin(gb, 1, f32);
    float mx = fmaxf(d0, d1);
    float e0 = __expf(d0 - mx), e1 = __expf(d1 - mx);
    float s = e0 + e1;
    float g0 = e0 / s, g1 = e1 / s;
    size_t base = (size_t)row * kD;
    xmid[base + i]       = ldin(X, base + i, f32)       + g0 * mo[base + i]       + g1 * cc[base + i];
    xmid[base + i + 256] = ldin(X, base + i + 256, f32) + g0 * mo[base + i + 256] + g1 * cc[base + i + 256];
}

// ---------------- launch ----------------
extern "C" void kernel_launch(void* const* d_in, const int* in_sizes, int n_in,
                              void* d_out, int out_size, void* d_ws, size_t ws_size,
                              hipStream_t stream) {
    // Input ordering: dict order (default) vs reference-signature order, detected via in_sizes[3].
    //   dict:      [x, n1g, n1b, fusion_w(524288), ...midblock..., fm_*(19..27), bm_*(28..36)]
    //   signature: [x, n1g, n1b, fm_in_w(1048576), ...fm/bm..., fusion_w(21), ...]
    bool sig = (n_in > 3 && in_sizes[3] == 2 * kDI * kD);
    int I_fusion_w = sig ? 21 : 3,  I_fusion_b = sig ? 22 : 4;
    int I_centers  = sig ? 23 : 5,  I_ccp_w    = sig ? 24 : 6,  I_ccp_b = sig ? 25 : 7;
    int I_ccn_g    = sig ? 26 : 8,  I_ccn_b    = sig ? 27 : 9,  I_alpha = sig ? 28 : 10;
    int I_gate_w   = sig ? 29 : 11, I_gate_b   = sig ? 30 : 12;
    int I_ffn_g    = sig ? 31 : 13, I_ffn_b    = sig ? 32 : 14;
    int I_ffn_w1   = sig ? 33 : 15, I_ffn_b1   = sig ? 34 : 16;
    int I_ffn_w2   = sig ? 35 : 17, I_ffn_b2   = sig ? 36 : 18;
    int I_fm       = sig ? 3  : 19, I_bm       = sig ? 12 : 28;

    const void* X        = d_in[0];
    const void* n1g      = d_in[1];
    const void* n1b      = d_in[2];
    const void* fusion_w = d_in[I_fusion_w];
    const void* fusion_b = d_in[I_fusion_b];
    const void* centers  = d_in[I_centers];
    const void* ccp_w    = d_in[I_ccp_w];
    const void* ccp_b    = d_in[I_ccp_b];
    const void* ccn_g    = d_in[I_ccn_g];
    const void* ccn_b    = d_in[I_ccn_b];
    const void* cc_alpha = d_in[I_alpha];
    const void* gate_w   = d_in[I_gate_w];
    const void* gate_b   = d_in[I_gate_b];
    const void* ffn_g    = d_in[I_ffn_g];
    const void* ffn_b    = d_in[I_ffn_b];
    const void* ffn_w1   = d_in[I_ffn_w1];
    const void* ffn_b1   = d_in[I_ffn_b1];
    const void* ffn_w2   = d_in[I_ffn_w2];
    const void* ffn_b2   = d_in[I_ffn_b2];

    float* ws = (float*)d_ws;
    int* flg  = (int*)d_ws;     // ws[0]
    float* cn = ws + 8;         // ws[8..15]
    // activations (fp32), aliased to fit ~67.6 MB
    float* xn    = ws + 32;                // 1048576
    float* xz    = xn    + 1048576;        // 4194304   (later: ffnh)
    float* xc    = xz    + 4194304;        // 2097152   (later: hln)
    float* xdbl  = xc    + 2097152;        // 131072
    float* delta = xdbl  + 131072;         // 2097152   (later: proj)
    float* ymul  = delta + 2097152;        // 2097152   (later: ccout)
    float* PA    = ymul  + 2097152;        // 1048576   (later: mo)
    float* HL    = PA    + 1048576;        // 1048576   (later: xmid)
    float* HIN   = HL    + 1048576;        // 1048576
    float* fb    = HIN   + 1048576;        // 2097152
    float* proj  = delta;
    float* ccout = ymul;
    float* mo    = PA;
    float* xmid  = HL;
    float* hln   = xc;
    float* ffnh  = xz;

    dim3 blk(256);

    detect_kernel<<<1, 64, 0, stream>>>((const unsigned short*)X, flg);

    // xn = LN(x)
    ln_in_kernel<<<kM, blk, 0, stream>>>(X, n1g, n1b, xn, flg);

    for (int dir = 0; dir < 2; ++dir) {
        int base = dir ? I_bm : I_fm;
        const void* in_w    = d_in[base + 0];
        const void* conv_w  = d_in[base + 1];
        const void* conv_b  = d_in[base + 2];
        const void* xproj_w = d_in[base + 3];
        const void* dt_w    = d_in[base + 4];
        const void* dt_b    = d_in[base + 5];
        const void* A_log   = d_in[base + 6];
        const void* Dp      = d_in[base + 7];
        const void* out_w   = d_in[base + 8];

        // xz = (dir? flip(xn) : xn) @ in_w.T   (M=2048, N=2048, K=512)
        gemm_kernel<<<dim3(2048 / 64, kM / 64), blk, 0, stream>>>(
            xn, kD, in_w, nullptr, kM, 2 * kDI, kD, 0, nullptr, xz, nullptr, 2 * kDI, dir, 0, flg);
        conv_kernel<<<kM * kDI / 256, blk, 0, stream>>>(xz, conv_w, conv_b, xc, flg);
        // x_dbl = xc @ xproj_w.T  (N=64, K=1024)
        gemm_kernel<<<dim3(1, kM / 64), blk, 0, stream>>>(
            xc, kDI, xproj_w, nullptr, kM, 64, kDI, 0, nullptr, xdbl, nullptr, 64, 0, 0, flg);
        // delta = softplus(dt @ dt_w.T + dt_b)  (N=1024, K=32)
        gemm_kernel<<<dim3(1024 / 64, kM / 64), blk, 0, stream>>>(
            xdbl, 64, dt_w, dt_b, kM, kDI, kDTR, 1, nullptr, delta, nullptr, kDI, 0, 0, flg);
        scan_phase1<<<kB * kCH * kDI / 256, blk, 0, stream>>>(delta, xc, xdbl, A_log, PA, HL, flg);
        scan_phase2<<<kB * kDI * kNS / 256, blk, 0, stream>>>(PA, HL, HIN);
        scan_phase3<<<kB * kCH * kDI / 256, blk, 0, stream>>>(delta, xc, xdbl, A_log, Dp, HIN,
                                                              xz, ymul, flg);
        // out = ymul @ out_w.T -> fb[:, dir*512 .. ], rows flipped back for bm
        gemm_kernel<<<dim3(512 / 64, kM / 64), blk, 0, stream>>>(
            ymul, kDI, out_w, nullptr, kM, kD, kDI, 0, nullptr, fb + dir * kD, nullptr, 2 * kD,
            0, dir, flg);
    }

    // mamba_out = fb @ fusion_w.T + fusion_b
    gemm_kernel<<<dim3(512 / 64, kM / 64), blk, 0, stream>>>(
        fb, 2 * kD, fusion_w, fusion_b, kM, kD, 2 * kD, 0, nullptr, mo, nullptr, kD, 0, 0, flg);

    // context clustering path
    gemm_kernel<<<dim3(512 / 64, kM / 64), blk, 0, stream>>>(
        xn, kD, ccp_w, ccp_b, kM, kD, kD, 0, nullptr, proj, nullptr, kD, 0, 0, flg);
    cnorm_kernel<<<kNC, 64, 0, stream>>>(centers, cn, flg);
    cc_kernel<<<kM, blk, 0, stream>>>(proj, centers, cn, xn, cc_alpha, ccn_g, ccn_b, ccout, flg);

    // gated fusion + residual -> xmid
    gate_kernel<<<kM, blk, 0, stream>>>(xn, X, mo, ccout, gate_w, gate_b, xmid, flg);

    // FFN
    ln_f32_kernel<<<kM, blk, 0, stream>>>(xmid, ffn_g, ffn_b, hln, flg);
    gemm_kernel<<<dim3(2048 / 64, kM / 64), blk, 0, stream>>>(
        hln, kD, ffn_w1, ffn_b1, kM, 4 * kD, kD, 2, nullptr, ffnh, nullptr, 4 * kD, 0, 0, flg);
    gemm_kernel<<<dim3(512 / 64, kM / 64), blk, 0, stream>>>(
        ffnh, 4 * kD, ffn_w2, ffn_b2, kM, kD, 4 * kD, 0, xmid, nullptr, d_out, kD, 0, 0, flg);
}

// Round 4
// 643.521 us; speedup vs baseline: 2.7763x; 2.7763x over previous
//
#include <hip/hip_runtime.h>
#include <hip/hip_bf16.h>
#include <math.h>

using bf16 = __hip_bfloat16;

typedef __attribute__((ext_vector_type(8))) short v8s;   // 8 bf16 = 4 VGPRs
typedef __attribute__((ext_vector_type(4))) float v4f;   // MFMA accumulator

// Problem constants
constexpr int kB   = 2;
constexpr int kL   = 1024;
constexpr int kD   = 512;    // d_model
constexpr int kDI  = 1024;   // inner dim
constexpr int kNS  = 16;     // d_state
constexpr int kDTR = 32;     // dt_rank
constexpr int kKC  = 4;      // conv width
constexpr int kNC  = 8;      // clusters
constexpr int kM   = kB * kL;  // 2048 rows
constexpr int kCH  = 32;       // scan chunks
constexpr int kCL  = kL / kCH; // 32 steps per chunk
constexpr float kEPS = 1e-5f;

static __device__ __forceinline__ float toF(bf16 x) { return __bfloat162float(x); }

// flag-dispatched raw-input load: flag=1 -> fp32, flag=0 -> bf16
static __device__ __forceinline__ float ldin(const void* p, int i, int f32) {
    if (f32) return ((const float*)p)[i];
    return toF(((const bf16*)p)[i]);
}

static __device__ __forceinline__ int flipL(int r) { return r ^ (kL - 1); }

// ---------------- dtype probe ----------------
__global__ void detect_kernel(const unsigned short* __restrict__ x, int* __restrict__ flag) {
    if (threadIdx.x == 0 && blockIdx.x == 0) {
        int plausible = 0;
        for (int i = 0; i < 512; ++i) {
            unsigned short h = x[2 * i];  // even (low) halves
            int e = (h >> 7) & 0xFF;
            if (e >= 100 && e <= 140) plausible++;
        }
        *flag = (plausible >= 256) ? 0 : 1;  // 0 = bf16, 1 = f32
    }
}

// ---------------- weight conversion to canonical bf16 ----------------
struct WSrcs { const void* p[12]; };

constexpr int kWOff[12] = {0, 1048576, 1114112, 1146880,
                           1671168, 2719744, 2785280, 2818048,
                           3342336, 3866624, 4128768, 5177344};
constexpr int kWTotal   = 6225920;  // bf16 elements

__global__ __launch_bounds__(256) void wconv_kernel(WSrcs s, bf16* __restrict__ dst,
                                                    const int* __restrict__ flg) {
    const int sz[12]  = {1048576, 65536, 32768, 524288, 1048576, 65536, 32768, 524288,
                         524288, 262144, 1048576, 1048576};
    const int off[12] = {0, 1048576, 1114112, 1146880, 1671168, 2719744, 2785280, 2818048,
                         3342336, 3866624, 4128768, 5177344};
    int t = blockIdx.y;
    int n = sz[t];
    const void* src = s.p[t];
    bf16* d = dst + off[t];
    int f32 = *flg;
    for (int i = blockIdx.x * 256 + threadIdx.x; i < n; i += gridDim.x * 256)
        d[i] = __float2bfloat16(ldin(src, i, f32));
}

// ---------------- block reduce (256 threads = 4 waves) ----------------
static __device__ __forceinline__ float blockReduceSum(float v, float* s) {
    __syncthreads();
#pragma unroll
    for (int o = 32; o > 0; o >>= 1) v += __shfl_down(v, o, 64);
    int lane = threadIdx.x & 63, wid = threadIdx.x >> 6;
    if (lane == 0) s[wid] = v;
    __syncthreads();
    if (threadIdx.x == 0) {
        float t = 0.f;
        for (int i = 0; i < 4; ++i) t += s[i];
        s[4] = t;
    }
    __syncthreads();
    return s[4];
}

// ---------------- LayerNorm on raw input -> bf16 ----------------
__global__ __launch_bounds__(256) void ln_in_kernel(const void* __restrict__ X,
                                                    const void* __restrict__ g,
                                                    const void* __restrict__ b,
                                                    bf16* __restrict__ Y,
                                                    const int* __restrict__ flg) {
    __shared__ float sred[8];
    int f32 = *flg;
    int row = blockIdx.x;
    int i = threadIdx.x;
    size_t base = (size_t)row * kD;
    float x0 = ldin(X, base + i, f32), x1 = ldin(X, base + i + 256, f32);
    float mean = blockReduceSum(x0 + x1, sred) * (1.f / kD);
    float vs = blockReduceSum(x0 * x0 + x1 * x1, sred) * (1.f / kD) - mean * mean;
    float rstd = rsqrtf(vs + kEPS);
    Y[base + i]       = __float2bfloat16((x0 - mean) * rstd * ldin(g, i, f32)       + ldin(b, i, f32));
    Y[base + i + 256] = __float2bfloat16((x1 - mean) * rstd * ldin(g, i + 256, f32) + ldin(b, i + 256, f32));
}

// ---------------- LayerNorm fp32 -> bf16 ----------------
__global__ __launch_bounds__(256) void ln_f32_kernel(const float* __restrict__ X,
                                                     const void* __restrict__ g,
                                                     const void* __restrict__ b,
                                                     bf16* __restrict__ Y,
                                                     const int* __restrict__ flg) {
    __shared__ float sred[8];
    int f32 = *flg;
    int row = blockIdx.x;
    int i = threadIdx.x;
    size_t base = (size_t)row * kD;
    float x0 = X[base + i], x1 = X[base + i + 256];
    float mean = blockReduceSum(x0 + x1, sred) * (1.f / kD);
    float vs = blockReduceSum(x0 * x0 + x1 * x1, sred) * (1.f / kD) - mean * mean;
    float rstd = rsqrtf(vs + kEPS);
    Y[base + i]       = __float2bfloat16((x0 - mean) * rstd * ldin(g, i, f32)       + ldin(b, i, f32));
    Y[base + i + 256] = __float2bfloat16((x1 - mean) * rstd * ldin(g, i + 256, f32) + ldin(b, i + 256, f32));
}

// ---------------- MFMA bf16 GEMM: out = act(A[M,K] @ W[N,K]^T + bias) (+resid) ----------------
// A bf16 row-major (lda), W bf16 row-major (ldw=K). 256 threads = 4 waves.
// BMxBN block tile, BK=64, 16x16x32 MFMA fragments. aflip: flip A rows in L; oflip: flip out rows.
template <int BM, int BN, int WRN, int WCN>
__global__ __launch_bounds__(256) void mfma_gemm(const bf16* __restrict__ A, int lda,
                                                 const bf16* __restrict__ W, int K,
                                                 const void* __restrict__ bias, int act,
                                                 const float* __restrict__ resid,
                                                 bf16* __restrict__ outB,
                                                 void* __restrict__ outRaw,
                                                 int ldo, int aflip, int oflip,
                                                 const int* __restrict__ flg) {
    __shared__ bf16 As[BM * 64];
    __shared__ bf16 Bs[BN * 64];
    constexpr int FR = BM / WRN / 16;
    constexpr int FC = BN / WCN / 16;
    constexpr int AV = BM * 8 / 256;  // bf16x8 vectors per thread for A tile
    constexpr int BV = BN * 8 / 256;

    int f32 = *flg;
    int tid = threadIdx.x;
    int m0 = blockIdx.y * BM, n0 = blockIdx.x * BN;
    int lane = tid & 63, w = tid >> 6;
    int wr = w % WRN, wc = w / WRN;
    int rbase = wr * (BM / WRN), cbase = wc * (BN / WCN);
    int quad = lane >> 4, lrow = lane & 15;

    v4f acc[FR][FC];
#pragma unroll
    for (int i = 0; i < FR; ++i)
#pragma unroll
        for (int j = 0; j < FC; ++j)
#pragma unroll
            for (int r = 0; r < 4; ++r) acc[i][j][r] = 0.f;

    for (int kt = 0; kt < K; kt += 64) {
        // stage A tile (BM x 64) and B tile (BN x 64)
#pragma unroll
        for (int i = 0; i < AV; ++i) {
            int v = i * 256 + tid;
            int row = v >> 3, c8 = (v & 7) * 8;
            int rg = m0 + row;
            if (aflip) rg = flipL(rg);
            v8s val = *reinterpret_cast<const v8s*>(A + (size_t)rg * lda + kt + c8);
            *reinterpret_cast<v8s*>(&As[row * 64 + c8]) = val;
        }
#pragma unroll
        for (int i = 0; i < BV; ++i) {
            int v = i * 256 + tid;
            int row = v >> 3, c8 = (v & 7) * 8;
            v8s val = *reinterpret_cast<const v8s*>(W + (size_t)(n0 + row) * K + kt + c8);
            *reinterpret_cast<v8s*>(&Bs[row * 64 + c8]) = val;
        }
        __syncthreads();
#pragma unroll
        for (int k0 = 0; k0 < 64; k0 += 32) {
            v8s a[FR], b[FC];
#pragma unroll
            for (int fr = 0; fr < FR; ++fr)
                a[fr] = *reinterpret_cast<const v8s*>(&As[(rbase + fr * 16 + lrow) * 64 + k0 + quad * 8]);
#pragma unroll
            for (int fc = 0; fc < FC; ++fc)
                b[fc] = *reinterpret_cast<const v8s*>(&Bs[(cbase + fc * 16 + lrow) * 64 + k0 + quad * 8]);
#pragma unroll
            for (int fr = 0; fr < FR; ++fr)
#pragma unroll
                for (int fc = 0; fc < FC; ++fc)
                    acc[fr][fc] = __builtin_amdgcn_mfma_f32_16x16x32_bf16(a[fr], b[fc], acc[fr][fc], 0, 0, 0);
        }
        __syncthreads();
    }

    // epilogue: C/D layout col=lane&15, row=quad*4+reg  [m89-verified]
#pragma unroll
    for (int fr = 0; fr < FR; ++fr) {
#pragma unroll
        for (int fc = 0; fc < FC; ++fc) {
            int n = n0 + cbase + fc * 16 + lrow;
            float bi = bias ? ldin(bias, n, f32) : 0.f;
#pragma unroll
            for (int r = 0; r < 4; ++r) {
                int m = m0 + rbase + fr * 16 + quad * 4 + r;
                float vv = acc[fr][fc][r] + bi;
                if (act == 2) vv = 0.5f * vv * (1.f + erff(vv * 0.70710678118654752440f));
                if (resid) vv += resid[(size_t)m * ldo + n];
                int mo_ = oflip ? flipL(m) : m;
                size_t oi = (size_t)mo_ * ldo + n;
                if (outB) outB[oi] = __float2bfloat16(vv);
                else if (f32) ((float*)outRaw)[oi] = vv;
                else ((bf16*)outRaw)[oi] = __float2bfloat16(vv);
            }
        }
    }
}

// ---------------- dt projection (K=32) + softplus -> fp32 delta ----------------
__global__ __launch_bounds__(256) void dt_kernel(const bf16* __restrict__ xdbl,
                                                 const bf16* __restrict__ wdt,
                                                 const void* __restrict__ dt_b,
                                                 float* __restrict__ delta,
                                                 const int* __restrict__ flg) {
    __shared__ float arow[kDTR];
    int f32 = *flg;
    int m = blockIdx.y;
    int n = blockIdx.x * 256 + threadIdx.x;
    if (threadIdx.x < kDTR) arow[threadIdx.x] = toF(xdbl[(size_t)m * 64 + threadIdx.x]);
    __syncthreads();
    float acc = ldin(dt_b, n, f32);
    const bf16* wr_ = wdt + (size_t)n * kDTR;
#pragma unroll
    for (int k = 0; k < kDTR; ++k) acc += arow[k] * toF(wr_[k]);
    acc = (acc > 20.f) ? acc : log1pf(__expf(acc));
    delta[(size_t)m * kDI + n] = acc;
}

// ---------------- depthwise causal conv + silu (bf16 in/out) ----------------
__global__ __launch_bounds__(256) void conv_kernel(const bf16* __restrict__ xz,
                                                   const void* __restrict__ cw,
                                                   const void* __restrict__ cb,
                                                   bf16* __restrict__ xc,
                                                   const int* __restrict__ flg) {
    int f32 = *flg;
    int tid = blockIdx.x * 256 + threadIdx.x;  // over kM*kDI
    int d = tid & (kDI - 1);
    int r = tid >> 10;
    int l = r & (kL - 1);
    int b = r >> 10;
    float acc = ldin(cb, d, f32);
#pragma unroll
    for (int k = 0; k < kKC; ++k) {
        int ll = l - (kKC - 1) + k;
        if (ll >= 0) acc += ldin(cw, d * kKC + k, f32) * toF(xz[((size_t)(b * kL + ll)) * (2 * kDI) + d]);
    }
    float s = acc / (1.f + __expf(-acc));
    xc[(size_t)r * kDI + d] = __float2bfloat16(s);
}

// ---------------- chunked selective scan ----------------
__global__ __launch_bounds__(256) void scan_phase1(const float* __restrict__ deltaF,
                                                   const bf16* __restrict__ xcF,
                                                   const bf16* __restrict__ xdbl,
                                                   const void* __restrict__ A_log,
                                                   float* __restrict__ PA,
                                                   float* __restrict__ HL,
                                                   const int* __restrict__ flg) {
    int f32 = *flg;
    int tid = blockIdx.x * 256 + threadIdx.x;  // B*CH*DI = 65536
    int d = tid & (kDI - 1);
    int rem = tid >> 10;
    int c = rem & (kCH - 1);
    int b = rem >> 5;
    float an[kNS], h[kNS], pa[kNS];
#pragma unroll
    for (int n = 0; n < kNS; ++n) {
        an[n] = -__expf(ldin(A_log, d * kNS + n, f32));
        h[n] = 0.f;
        pa[n] = 1.f;
    }
    int l0 = c * kCL;
    for (int l = l0; l < l0 + kCL; ++l) {
        size_t rb = (size_t)(b * kL + l);
        float dl = deltaF[rb * kDI + d];
        float xcv = toF(xcF[rb * kDI + d]);
        float du = dl * xcv;
        const bf16* Bp = xdbl + rb * 64 + kDTR;
#pragma unroll
        for (int n = 0; n < kNS; ++n) {
            float a = __expf(dl * an[n]);
            pa[n] *= a;
            h[n] = a * h[n] + du * toF(Bp[n]);
        }
    }
    size_t o = (((size_t)(b * kDI + d)) * kCH + c) * kNS;
#pragma unroll
    for (int n = 0; n < kNS; ++n) { PA[o + n] = pa[n]; HL[o + n] = h[n]; }
}

__global__ __launch_bounds__(256) void scan_phase2(const float* __restrict__ PA,
                                                   const float* __restrict__ HL,
                                                   float* __restrict__ HIN) {
    int tid = blockIdx.x * 256 + threadIdx.x;  // B*DI*NS = 32768
    int n = tid & (kNS - 1);
    int d = (tid >> 4) & (kDI - 1);
    int b = tid >> 14;
    float h = 0.f;
    size_t base = ((size_t)(b * kDI + d)) * kCH * kNS + n;
    for (int c = 0; c < kCH; ++c) {
        size_t idx = base + (size_t)c * kNS;
        HIN[idx] = h;
        h = PA[idx] * h + HL[idx];
    }
}

__global__ __launch_bounds__(256) void scan_phase3(const float* __restrict__ deltaF,
                                                   const bf16* __restrict__ xcF,
                                                   const bf16* __restrict__ xdbl,
                                                   const void* __restrict__ A_log,
                                                   const void* __restrict__ Dp,
                                                   const float* __restrict__ HIN,
                                                   const bf16* __restrict__ xz,
                                                   bf16* __restrict__ ymul,
                                                   const int* __restrict__ flg) {
    int f32 = *flg;
    int tid = blockIdx.x * 256 + threadIdx.x;
    int d = tid & (kDI - 1);
    int rem = tid >> 10;
    int c = rem & (kCH - 1);
    int b = rem >> 5;
    float an[kNS], h[kNS];
    size_t o = (((size_t)(b * kDI + d)) * kCH + c) * kNS;
#pragma unroll
    for (int n = 0; n < kNS; ++n) {
        an[n] = -__expf(ldin(A_log, d * kNS + n, f32));
        h[n] = HIN[o + n];
    }
    float Dv = ldin(Dp, d, f32);
    int l0 = c * kCL;
    for (int l = l0; l < l0 + kCL; ++l) {
        size_t rb = (size_t)(b * kL + l);
        float dl = deltaF[rb * kDI + d];
        float xcv = toF(xcF[rb * kDI + d]);
        float du = dl * xcv;
        const bf16* Bp = xdbl + rb * 64 + kDTR;
        const bf16* Cp = xdbl + rb * 64 + kDTR + kNS;
        float y = 0.f;
#pragma unroll
        for (int n = 0; n < kNS; ++n) {
            float a = __expf(dl * an[n]);
            h[n] = a * h[n] + du * toF(Bp[n]);
            y += h[n] * toF(Cp[n]);
        }
        y += xcv * Dv;
        float zv = toF(xz[rb * (2 * kDI) + kDI + d]);
        float sz = zv / (1.f + __expf(-zv));
        ymul[rb * kDI + d] = __float2bfloat16(y * sz);
    }
}

// ---------------- cluster-center norms ----------------
__global__ void cnorm_kernel(const void* __restrict__ C, float* __restrict__ cn,
                             const int* __restrict__ flg) {
    int f32 = *flg;
    int c = blockIdx.x;
    int lane = threadIdx.x;  // 64 threads
    float s = 0.f;
    for (int i = lane; i < kD; i += 64) {
        float v = ldin(C, c * kD + i, f32);
        s += v * v;
    }
#pragma unroll
    for (int o = 32; o > 0; o >>= 1) s += __shfl_down(s, o, 64);
    if (lane == 0) cn[c] = sqrtf(s);
}

// ---------------- context clustering ----------------
__global__ __launch_bounds__(256) void cc_kernel(const bf16* __restrict__ proj,
                                                 const void* __restrict__ centers,
                                                 const float* __restrict__ cn,
                                                 const bf16* __restrict__ xn,
                                                 const void* __restrict__ alpha_p,
                                                 const void* __restrict__ g,
                                                 const void* __restrict__ bb,
                                                 bf16* __restrict__ ccout,
                                                 const int* __restrict__ flg) {
    __shared__ float sred[8];
    __shared__ float sims[kNC];
    int f32 = *flg;
    int row = blockIdx.x;
    int i = threadIdx.x;
    size_t base = (size_t)row * kD;
    float p0 = toF(proj[base + i]), p1 = toF(proj[base + i + 256]);
    float sumsq = blockReduceSum(p0 * p0 + p1 * p1, sred);
    float pn = fmaxf(sqrtf(sumsq), 1e-12f);
    for (int c = 0; c < kNC; ++c) {
        float part = p0 * ldin(centers, c * kD + i, f32) + p1 * ldin(centers, c * kD + i + 256, f32);
        float dot = blockReduceSum(part, sred);
        if (threadIdx.x == 0) sims[c] = dot / (pn * fmaxf(cn[c], 1e-12f));
    }
    __syncthreads();
    float mx = -1e30f;
#pragma unroll
    for (int c = 0; c < kNC; ++c) mx = fmaxf(mx, sims[c]);
    float wv[kNC], se = 0.f;
#pragma unroll
    for (int c = 0; c < kNC; ++c) { wv[c] = __expf(sims[c] - mx); se += wv[c]; }
    float inv = 1.f / se;
    float ctx0 = 0.f, ctx1 = 0.f;
#pragma unroll
    for (int c = 0; c < kNC; ++c) {
        float wc = wv[c] * inv;
        ctx0 += wc * ldin(centers, c * kD + i, f32);
        ctx1 += wc * ldin(centers, c * kD + i + 256, f32);
    }
    float alpha = ldin(alpha_p, 0, f32);
    float t0 = toF(xn[base + i]) + alpha * ctx0;
    float t1 = toF(xn[base + i + 256]) + alpha * ctx1;
    float mean = blockReduceSum(t0 + t1, sred) * (1.f / kD);
    float vs = blockReduceSum(t0 * t0 + t1 * t1, sred) * (1.f / kD) - mean * mean;
    float rstd = rsqrtf(vs + kEPS);
    ccout[base + i]       = __float2bfloat16((t0 - mean) * rstd * ldin(g, i, f32)       + ldin(bb, i, f32));
    ccout[base + i + 256] = __float2bfloat16((t1 - mean) * rstd * ldin(g, i + 256, f32) + ldin(bb, i + 256, f32));
}

// ---------------- gated fusion + residual -> fp32 xmid ----------------
__global__ __launch_bounds__(256) void gate_kernel(const bf16* __restrict__ xn,
                                                   const void* __restrict__ X,
                                                   const bf16* __restrict__ mo,
                                                   const bf16* __restrict__ cc,
                                                   const void* __restrict__ gw,
                                                   const void* __restrict__ gb,
                                                   float* __restrict__ xmid,
                                                   const int* __restrict__ flg) {
    __shared__ float sred[8];
    int f32 = *flg;
    int row = blockIdx.x;
    int i = threadIdx.x;
    size_t base = (size_t)row * kD;
    float x0 = toF(xn[base + i]), x1 = toF(xn[base + i + 256]);
    float d0 = blockReduceSum(x0 * ldin(gw, i, f32) + x1 * ldin(gw, i + 256, f32), sred);
    float d1 = blockReduceSum(x0 * ldin(gw, kD + i, f32) + x1 * ldin(gw, kD + i + 256, f32), sred);
    d0 += ldin(gb, 0, f32);
    d1 += ldin(gb, 1, f32);
    float mx = fmaxf(d0, d1);
    float e0 = __expf(d0 - mx), e1 = __expf(d1 - mx);
    float s = e0 + e1;
    float g0 = e0 / s, g1 = e1 / s;
    xmid[base + i]       = ldin(X, base + i, f32)       + g0 * toF(mo[base + i])       + g1 * toF(cc[base + i]);
    xmid[base + i + 256] = ldin(X, base + i + 256, f32) + g0 * toF(mo[base + i + 256]) + g1 * toF(cc[base + i + 256]);
}

// ---------------- launch ----------------
extern "C" void kernel_launch(void* const* d_in, const int* in_sizes, int n_in,
                              void* d_out, int out_size, void* d_ws, size_t ws_size,
                              hipStream_t stream) {
    bool sig = (n_in > 3 && in_sizes[3] == 2 * kDI * kD);
    int I_fusion_w = sig ? 21 : 3,  I_fusion_b = sig ? 22 : 4;
    int I_centers  = sig ? 23 : 5,  I_ccp_w    = sig ? 24 : 6,  I_ccp_b = sig ? 25 : 7;
    int I_ccn_g    = sig ? 26 : 8,  I_ccn_b    = sig ? 27 : 9,  I_alpha = sig ? 28 : 10;
    int I_gate_w   = sig ? 29 : 11, I_gate_b   = sig ? 30 : 12;
    int I_ffn_g    = sig ? 31 : 13, I_ffn_b    = sig ? 32 : 14;
    int I_ffn_w1   = sig ? 33 : 15, I_ffn_b1   = sig ? 34 : 16;
    int I_ffn_w2   = sig ? 35 : 17, I_ffn_b2   = sig ? 36 : 18;
    int I_fm       = sig ? 3  : 19, I_bm       = sig ? 12 : 28;

    const void* X        = d_in[0];
    const void* n1g      = d_in[1];
    const void* n1b      = d_in[2];
    const void* fusion_b = d_in[I_fusion_b];
    const void* centers  = d_in[I_centers];
    const void* ccp_b    = d_in[I_ccp_b];
    const void* ccn_g    = d_in[I_ccn_g];
    const void* ccn_b    = d_in[I_ccn_b];
    const void* cc_alpha = d_in[I_alpha];
    const void* gate_w   = d_in[I_gate_w];
    const void* gate_b   = d_in[I_gate_b];
    const void* ffn_g    = d_in[I_ffn_g];
    const void* ffn_b    = d_in[I_ffn_b];
    const void* ffn_b1   = d_in[I_ffn_b1];
    const void* ffn_b2   = d_in[I_ffn_b2];

    // ---- workspace layout (FLOAT units; bf16 regions use count/2 floats) ----
    float* ws = (float*)d_ws;
    int* flg  = (int*)d_ws;           // ws[0]
    float* cn = ws + 8;               // 8 floats
    float* delta = ws + 32;                         // 2,097,152 f32 (8 MB)
    float* PA    = delta + 2097152;                 // 1,048,576 f32
    float* HL    = PA    + 1048576;                 // 1,048,576 f32
    float* HIN   = HL    + 1048576;                 // 1,048,576 f32
    bf16*  xn    = (bf16*)(HIN + 1048576);          // 1,048,576 bf16 = 524,288 f
    bf16*  xz    = (bf16*)((float*)xn + 524288);    // 4,194,304 bf16 = 2,097,152 f
    bf16*  xc    = (bf16*)((float*)xz + 2097152);   // 2,097,152 bf16 = 1,048,576 f
    bf16*  xdbl  = (bf16*)((float*)xc + 1048576);   // 131,072 bf16 = 65,536 f
    bf16*  ymul  = (bf16*)((float*)xdbl + 65536);   // 2,097,152 bf16 = 1,048,576 f
    bf16*  fb    = (bf16*)((float*)ymul + 1048576); // 2,097,152 bf16 = 1,048,576 f
    bf16*  wbuf  = (bf16*)((float*)fb + 1048576);   // 6,225,920 bf16 = 3,112,960 f
    // total = 14,188,576 floats = 56.8 MB (round-2 proved ws >= 67.6 MB)
    // aliases of dead regions (all size-checked):
    bf16*  mo    = (bf16*)PA;      // 1,048,576 bf16 <= 1,048,576 f   (PA dead after scan)
    float* xmid  = HL;             // 1,048,576 f32 exact             (HL dead after scan)
    bf16*  hln   = xc;             // 1,048,576 bf16 <= xc region     (xc dead after dir loop)
    bf16*  ffnh  = xz;             // 4,194,304 bf16 exact            (xz dead after dir loop)
    bf16*  ccout = ymul;           // 1,048,576 bf16 <= ymul region   (ymul dead after out-proj)

    // weight bf16 views
    bf16* w_fm_in    = wbuf + kWOff[0];
    bf16* w_fm_xproj = wbuf + kWOff[1];
    bf16* w_fm_dt    = wbuf + kWOff[2];
    bf16* w_fm_out   = wbuf + kWOff[3];
    bf16* w_bm_in    = wbuf + kWOff[4];
    bf16* w_bm_xproj = wbuf + kWOff[5];
    bf16* w_bm_dt    = wbuf + kWOff[6];
    bf16* w_bm_out   = wbuf + kWOff[7];
    bf16* w_fusion   = wbuf + kWOff[8];
    bf16* w_ccp      = wbuf + kWOff[9];
    bf16* w_ffn1     = wbuf + kWOff[10];
    bf16* w_ffn2     = wbuf + kWOff[11];

    dim3 blk(256);

    detect_kernel<<<1, 64, 0, stream>>>((const unsigned short*)X, flg);

    WSrcs srcs;
    srcs.p[0] = d_in[I_fm + 0]; srcs.p[1] = d_in[I_fm + 3]; srcs.p[2] = d_in[I_fm + 4]; srcs.p[3] = d_in[I_fm + 8];
    srcs.p[4] = d_in[I_bm + 0]; srcs.p[5] = d_in[I_bm + 3]; srcs.p[6] = d_in[I_bm + 4]; srcs.p[7] = d_in[I_bm + 8];
    srcs.p[8] = d_in[I_fusion_w]; srcs.p[9] = d_in[I_ccp_w]; srcs.p[10] = d_in[I_ffn_w1]; srcs.p[11] = d_in[I_ffn_w2];
    wconv_kernel<<<dim3(512, 12), blk, 0, stream>>>(srcs, wbuf, flg);

    // xn = LN(x)
    ln_in_kernel<<<kM, blk, 0, stream>>>(X, n1g, n1b, xn, flg);

    for (int dir = 0; dir < 2; ++dir) {
        int base = dir ? I_bm : I_fm;
        const void* conv_w = d_in[base + 1];
        const void* conv_b = d_in[base + 2];
        const void* dt_b   = d_in[base + 5];
        const void* A_log  = d_in[base + 6];
        const void* Dp     = d_in[base + 7];
        bf16* w_in  = dir ? w_bm_in : w_fm_in;
        bf16* w_xp  = dir ? w_bm_xproj : w_fm_xproj;
        bf16* w_dt  = dir ? w_bm_dt : w_fm_dt;
        bf16* w_out = dir ? w_bm_out : w_fm_out;

        // xz = (dir? flip(xn) : xn) @ in_w.T  (2048 x 2048 x 512)
        mfma_gemm<128, 128, 2, 2><<<dim3(2048 / 128, kM / 128), blk, 0, stream>>>(
            xn, kD, w_in, kD, nullptr, 0, nullptr, xz, nullptr, 2 * kDI, dir, 0, flg);
        conv_kernel<<<kM * kDI / 256, blk, 0, stream>>>(xz, conv_w, conv_b, xc, flg);
        // x_dbl = xc @ xproj_w.T  (2048 x 64 x 1024)
        mfma_gemm<64, 64, 2, 2><<<dim3(1, kM / 64), blk, 0, stream>>>(
            xc, kDI, w_xp, kDI, nullptr, 0, nullptr, xdbl, nullptr, 64, 0, 0, flg);
        // delta = softplus(dt @ dt_w.T + dt_b)  (2048 x 1024 x 32)
        dt_kernel<<<dim3(kDI / 256, kM), blk, 0, stream>>>(xdbl, w_dt, dt_b, delta, flg);
        scan_phase1<<<kB * kCH * kDI / 256, blk, 0, stream>>>(delta, xc, xdbl, A_log, PA, HL, flg);
        scan_phase2<<<kB * kDI * kNS / 256, blk, 0, stream>>>(PA, HL, HIN);
        scan_phase3<<<kB * kCH * kDI / 256, blk, 0, stream>>>(delta, xc, xdbl, A_log, Dp, HIN,
                                                              xz, ymul, flg);
        // out = ymul @ out_w.T -> fb[:, dir*512..], rows flipped back for bm  (2048 x 512 x 1024)
        mfma_gemm<64, 64, 2, 2><<<dim3(kD / 64, kM / 64), blk, 0, stream>>>(
            ymul, kDI, w_out, kDI, nullptr, 0, nullptr, fb + dir * kD, nullptr, 2 * kD, 0, dir, flg);
    }

    // mamba_out = fb @ fusion_w.T + fusion_b  (2048 x 512 x 1024)
    mfma_gemm<64, 64, 2, 2><<<dim3(kD / 64, kM / 64), blk, 0, stream>>>(
        fb, 2 * kD, w_fusion, 2 * kD, fusion_b, 0, nullptr, mo, nullptr, kD, 0, 0, flg);

    // proj = xn @ ccp_w.T + ccp_b  (2048 x 512 x 512) -> alias delta (dead after dir loop)
    bf16* projb = (bf16*)delta;
    mfma_gemm<64, 64, 2, 2><<<dim3(kD / 64, kM / 64), blk, 0, stream>>>(
        xn, kD, w_ccp, kD, ccp_b, 0, nullptr, projb, nullptr, kD, 0, 0, flg);
    cnorm_kernel<<<kNC, 64, 0, stream>>>(centers, cn, flg);
    cc_kernel<<<kM, blk, 0, stream>>>(projb, centers, cn, xn, cc_alpha, ccn_g, ccn_b, ccout, flg);

    // gated fusion + residual -> xmid (fp32)
    gate_kernel<<<kM, blk, 0, stream>>>(xn, X, mo, ccout, gate_w, gate_b, xmid, flg);

    // FFN
    ln_f32_kernel<<<kM, blk, 0, stream>>>(xmid, ffn_g, ffn_b, hln, flg);
    mfma_gemm<128, 128, 2, 2><<<dim3(2048 / 128, kM / 128), blk, 0, stream>>>(
        hln, kD, w_ffn1, kD, ffn_b1, 2, nullptr, ffnh, nullptr, 4 * kD, 0, 0, flg);
    mfma_gemm<64, 64, 2, 2><<<dim3(kD / 64, kM / 64), blk, 0, stream>>>(
        ffnh, 4 * kD, w_ffn2, 4 * kD, ffn_b2, 0, xmid, nullptr, d_out, kD, 0, 0, flg);
}

// Round 5
// 492.208 us; speedup vs baseline: 3.6297x; 1.3074x over previous
//
#include <hip/hip_runtime.h>
#include <hip/hip_bf16.h>
#include <math.h>

using bf16 = __hip_bfloat16;

typedef __attribute__((ext_vector_type(8))) short v8s;   // 8 bf16 = 4 VGPRs
typedef __attribute__((ext_vector_type(4))) float v4f;   // MFMA accumulator

// Problem constants
constexpr int kB   = 2;
constexpr int kL   = 1024;
constexpr int kD   = 512;    // d_model
constexpr int kDI  = 1024;   // inner dim
constexpr int kNS  = 16;     // d_state
constexpr int kDTR = 32;     // dt_rank
constexpr int kKC  = 4;      // conv width
constexpr int kNC  = 8;      // clusters
constexpr int kM   = kB * kL;  // 2048 rows
constexpr int kCH  = 16;       // scan chunks
constexpr int kCL  = kL / kCH; // 64 steps per chunk
constexpr float kEPS = 1e-5f;

static __device__ __forceinline__ float toF(bf16 x) { return __bfloat162float(x); }

// flag-dispatched raw-input load: flag=1 -> fp32, flag=0 -> bf16
static __device__ __forceinline__ float ldin(const void* p, int i, int f32) {
    if (f32) return ((const float*)p)[i];
    return toF(((const bf16*)p)[i]);
}

static __device__ __forceinline__ int flipL(int r) { return r ^ (kL - 1); }

// ---------------- dtype probe ----------------
__global__ void detect_kernel(const unsigned short* __restrict__ x, int* __restrict__ flag) {
    if (threadIdx.x == 0 && blockIdx.x == 0) {
        int plausible = 0;
        for (int i = 0; i < 512; ++i) {
            unsigned short h = x[2 * i];  // even (low) halves
            int e = (h >> 7) & 0xFF;
            if (e >= 100 && e <= 140) plausible++;
        }
        *flag = (plausible >= 256) ? 0 : 1;  // 0 = bf16, 1 = f32
    }
}

// ---------------- weight conversion to canonical bf16 ----------------
// order: fm_in, bm_in, fm_xproj, bm_xproj, fm_dt, bm_dt, fm_out, bm_out, fusion, ccp, ffn1, ffn2
struct WSrcs { const void* p[12]; };

__global__ __launch_bounds__(256) void wconv_kernel(WSrcs s, bf16* __restrict__ dst,
                                                    const int* __restrict__ flg) {
    const int sz[12]  = {1048576, 1048576, 65536, 65536, 32768, 32768,
                         524288, 524288, 524288, 262144, 1048576, 1048576};
    const int off[12] = {0, 1048576, 2097152, 2162688, 2228224, 2260992,
                         2293760, 2818048, 3342336, 3866624, 4128768, 5177344};
    int t = blockIdx.y;
    int n = sz[t];
    const void* src = s.p[t];
    bf16* d = dst + off[t];
    int f32 = *flg;
    for (int i = blockIdx.x * 256 + threadIdx.x; i < n; i += gridDim.x * 256)
        d[i] = __float2bfloat16(ldin(src, i, f32));
}

// ---------------- block reduce (256 threads = 4 waves) ----------------
static __device__ __forceinline__ float blockReduceSum(float v, float* s) {
    __syncthreads();
#pragma unroll
    for (int o = 32; o > 0; o >>= 1) v += __shfl_down(v, o, 64);
    int lane = threadIdx.x & 63, wid = threadIdx.x >> 6;
    if (lane == 0) s[wid] = v;
    __syncthreads();
    if (threadIdx.x == 0) {
        float t = 0.f;
        for (int i = 0; i < 4; ++i) t += s[i];
        s[4] = t;
    }
    __syncthreads();
    return s[4];
}

// ---------------- LayerNorm on raw input -> bf16 ----------------
__global__ __launch_bounds__(256) void ln_in_kernel(const void* __restrict__ X,
                                                    const void* __restrict__ g,
                                                    const void* __restrict__ b,
                                                    bf16* __restrict__ Y,
                                                    const int* __restrict__ flg) {
    __shared__ float sred[8];
    int f32 = *flg;
    int row = blockIdx.x;
    int i = threadIdx.x;
    size_t base = (size_t)row * kD;
    float x0 = ldin(X, base + i, f32), x1 = ldin(X, base + i + 256, f32);
    float mean = blockReduceSum(x0 + x1, sred) * (1.f / kD);
    float vs = blockReduceSum(x0 * x0 + x1 * x1, sred) * (1.f / kD) - mean * mean;
    float rstd = rsqrtf(vs + kEPS);
    Y[base + i]       = __float2bfloat16((x0 - mean) * rstd * ldin(g, i, f32)       + ldin(b, i, f32));
    Y[base + i + 256] = __float2bfloat16((x1 - mean) * rstd * ldin(g, i + 256, f32) + ldin(b, i + 256, f32));
}

// ---------------- LayerNorm fp32 -> bf16 ----------------
__global__ __launch_bounds__(256) void ln_f32_kernel(const float* __restrict__ X,
                                                     const void* __restrict__ g,
                                                     const void* __restrict__ b,
                                                     bf16* __restrict__ Y,
                                                     const int* __restrict__ flg) {
    __shared__ float sred[8];
    int f32 = *flg;
    int row = blockIdx.x;
    int i = threadIdx.x;
    size_t base = (size_t)row * kD;
    float x0 = X[base + i], x1 = X[base + i + 256];
    float mean = blockReduceSum(x0 + x1, sred) * (1.f / kD);
    float vs = blockReduceSum(x0 * x0 + x1 * x1, sred) * (1.f / kD) - mean * mean;
    float rstd = rsqrtf(vs + kEPS);
    Y[base + i]       = __float2bfloat16((x0 - mean) * rstd * ldin(g, i, f32)       + ldin(b, i, f32));
    Y[base + i + 256] = __float2bfloat16((x1 - mean) * rstd * ldin(g, i + 256, f32) + ldin(b, i + 256, f32));
}

// ---------------- MFMA bf16 GEMM with z-batch + global_load_lds staging ----------------
// out[z] = act(A[z][M,K] @ W[z][N,K]^T + bias) (+resid). Output rows flipped for
// columns >= flipN0 or (zflip && z==1).
template <int BM, int BN, int WRN, int WCN>
__global__ __launch_bounds__(256) void mfma_gemm(const bf16* __restrict__ A, int lda, int aZOff,
                                                 const bf16* __restrict__ W, int K, int wZOff,
                                                 const void* __restrict__ bias, int act,
                                                 const float* __restrict__ resid,
                                                 bf16* __restrict__ outB,
                                                 void* __restrict__ outRaw,
                                                 int ldo, int oZOff,
                                                 int flipN0, int zflip,
                                                 const int* __restrict__ flg) {
    __shared__ bf16 As[BM * 64];
    __shared__ bf16 Bs[BN * 64];
    constexpr int FR = BM / WRN / 16;
    constexpr int FC = BN / WCN / 16;
    constexpr int AV = BM / 32;  // 16B chunks per thread for A tile
    constexpr int BV = BN / 32;

    int f32 = *flg;
    int tid = threadIdx.x;
    int z = blockIdx.z;
    const bf16* Ab = A + (size_t)z * aZOff;
    const bf16* Wb = W + (size_t)z * wZOff;
    int m0 = blockIdx.y * BM, n0 = blockIdx.x * BN;
    int lane = tid & 63, w = tid >> 6;
    int wr = w % WRN, wc = w / WRN;
    int rbase = wr * (BM / WRN), cbase = wc * (BN / WCN);
    int quad = lane >> 4, lrow = lane & 15;
    int wbase = tid & ~63;  // wave-uniform

    v4f acc[FR][FC];
#pragma unroll
    for (int i = 0; i < FR; ++i)
#pragma unroll
        for (int j = 0; j < FC; ++j)
#pragma unroll
            for (int r = 0; r < 4; ++r) acc[i][j][r] = 0.f;

    for (int kt = 0; kt < K; kt += 64) {
        // async stage A tile (BM x 64) and B tile (BN x 64): wave-uniform LDS base + lane*16
#pragma unroll
        for (int i = 0; i < AV; ++i) {
            int v = i * 256 + tid;
            int row = v >> 3, c8 = (v & 7) * 8;
            const bf16* gp = Ab + (size_t)(m0 + row) * lda + kt + c8;
            __builtin_amdgcn_global_load_lds(
                (const __attribute__((address_space(1))) void*)gp,
                (__attribute__((address_space(3))) void*)&As[(i * 256 + wbase) * 8],
                16, 0, 0);
        }
#pragma unroll
        for (int i = 0; i < BV; ++i) {
            int v = i * 256 + tid;
            int row = v >> 3, c8 = (v & 7) * 8;
            const bf16* gp = Wb + (size_t)(n0 + row) * K + kt + c8;
            __builtin_amdgcn_global_load_lds(
                (const __attribute__((address_space(1))) void*)gp,
                (__attribute__((address_space(3))) void*)&Bs[(i * 256 + wbase) * 8],
                16, 0, 0);
        }
        __syncthreads();
#pragma unroll
        for (int k0 = 0; k0 < 64; k0 += 32) {
            v8s a[FR], b[FC];
#pragma unroll
            for (int fr = 0; fr < FR; ++fr)
                a[fr] = *reinterpret_cast<const v8s*>(&As[(rbase + fr * 16 + lrow) * 64 + k0 + quad * 8]);
#pragma unroll
            for (int fc = 0; fc < FC; ++fc)
                b[fc] = *reinterpret_cast<const v8s*>(&Bs[(cbase + fc * 16 + lrow) * 64 + k0 + quad * 8]);
#pragma unroll
            for (int fr = 0; fr < FR; ++fr)
#pragma unroll
                for (int fc = 0; fc < FC; ++fc)
                    acc[fr][fc] = __builtin_amdgcn_mfma_f32_16x16x32_bf16(a[fr], b[fc], acc[fr][fc], 0, 0, 0);
        }
        __syncthreads();
    }

    // epilogue: C/D layout col=lane&15, row=quad*4+reg  [m89-verified]
    bf16* outBz = outB ? outB + (size_t)z * oZOff : nullptr;
#pragma unroll
    for (int fr = 0; fr < FR; ++fr) {
#pragma unroll
        for (int fc = 0; fc < FC; ++fc) {
            int ncol = n0 + cbase + fc * 16 + lrow;
            float bi = bias ? ldin(bias, ncol, f32) : 0.f;
            bool doflip = (ncol >= flipN0) || (zflip && z == 1);
#pragma unroll
            for (int r = 0; r < 4; ++r) {
                int m = m0 + rbase + fr * 16 + quad * 4 + r;
                float vv = acc[fr][fc][r] + bi;
                if (act == 2) vv = 0.5f * vv * (1.f + erff(vv * 0.70710678118654752440f));
                if (resid) vv += resid[(size_t)m * ldo + ncol];
                int mo_ = doflip ? flipL(m) : m;
                size_t oi = (size_t)mo_ * ldo + ncol;
                if (outBz) outBz[oi] = __float2bfloat16(vv);
                else if (f32) ((float*)outRaw)[oi] = vv;
                else ((bf16*)outRaw)[oi] = __float2bfloat16(vv);
            }
        }
    }
}

// ---------------- depthwise causal conv + silu, both dirs ----------------
// xz: (2048 x 4096) = [xp_f | z_f | xp_b | z_b]; xc: (2048 x 2048) = [xc_f | xc_b]
__global__ __launch_bounds__(256) void conv_kernel(const bf16* __restrict__ xz,
                                                   const void* __restrict__ cw_f,
                                                   const void* __restrict__ cb_f,
                                                   const void* __restrict__ cw_b,
                                                   const void* __restrict__ cb_b,
                                                   bf16* __restrict__ xc,
                                                   const int* __restrict__ flg) {
    int f32 = *flg;
    int tid = blockIdx.x * 256 + threadIdx.x;  // 2*kM*kDI
    int d = tid & (kDI - 1);
    int r = (tid >> 10) & (kM - 1);
    int dir = tid >> 21;
    int l = r & (kL - 1);
    int b = r >> 10;
    const void* cw = dir ? cw_b : cw_f;
    const void* cb = dir ? cb_b : cb_f;
    float acc = ldin(cb, d, f32);
#pragma unroll
    for (int k = 0; k < kKC; ++k) {
        int ll = l - (kKC - 1) + k;
        if (ll >= 0)
            acc += ldin(cw, d * kKC + k, f32) *
                   toF(xz[(size_t)(b * kL + ll) * (4 * kDI) + dir * 2048 + d]);
    }
    float s = acc / (1.f + __expf(-acc));
    xc[(size_t)r * (2 * kDI) + dir * kDI + d] = __float2bfloat16(s);
}

// ---------------- chunked selective scan (delta computed inline) ----------------
// xdbl: (2048 x 128) = [dt_f(32)|B_f(16)|C_f(16) | dt_b|B_b|C_b]
__global__ __launch_bounds__(256) void scan_phase1(const bf16* __restrict__ xc,
                                                   const bf16* __restrict__ xdbl,
                                                   const bf16* __restrict__ wdt,
                                                   const void* __restrict__ dtb_f,
                                                   const void* __restrict__ dtb_b,
                                                   const void* __restrict__ alog_f,
                                                   const void* __restrict__ alog_b,
                                                   float* __restrict__ PA,
                                                   float* __restrict__ HL,
                                                   const int* __restrict__ flg) {
    int f32 = *flg;
    int tid = blockIdx.x * 256 + threadIdx.x;  // 2*2*16*1024 = 65536
    int d   = tid & (kDI - 1);
    int c   = (tid >> 10) & (kCH - 1);
    int b   = (tid >> 14) & 1;
    int dir = tid >> 15;
    const void* alog = dir ? alog_b : alog_f;
    float dtb_v = ldin(dir ? dtb_b : dtb_f, d, f32);
    float wreg[kDTR];
    const bf16* wrow = wdt + ((size_t)dir * kDI + d) * kDTR;
#pragma unroll
    for (int k = 0; k < kDTR; ++k) wreg[k] = toF(wrow[k]);
    float an[kNS], h[kNS], pa[kNS];
#pragma unroll
    for (int n = 0; n < kNS; ++n) {
        an[n] = -__expf(ldin(alog, d * kNS + n, f32));
        h[n] = 0.f;
        pa[n] = 1.f;
    }
    int l0 = c * kCL;
    for (int l = l0; l < l0 + kCL; ++l) {
        size_t rb = (size_t)b * kL + l;
        const bf16* xrow = xdbl + rb * 128 + dir * 64;
        float accd = dtb_v;
#pragma unroll
        for (int k = 0; k < kDTR; ++k) accd += toF(xrow[k]) * wreg[k];
        float dl = (accd > 20.f) ? accd : log1pf(__expf(accd));
        float xcv = toF(xc[rb * (2 * kDI) + dir * kDI + d]);
        float du = dl * xcv;
        const bf16* Bp = xrow + kDTR;
#pragma unroll
        for (int n = 0; n < kNS; ++n) {
            float a = __expf(dl * an[n]);
            pa[n] *= a;
            h[n] = a * h[n] + du * toF(Bp[n]);
        }
    }
    int sid = ((dir * kB + b) << 10) + d;
    size_t o = ((size_t)sid * kCH + c) * kNS;
#pragma unroll
    for (int n = 0; n < kNS; ++n) { PA[o + n] = pa[n]; HL[o + n] = h[n]; }
}

// combine over chunks; write HIN in-place into PA
__global__ __launch_bounds__(256) void scan_phase2(float* __restrict__ PA,
                                                   const float* __restrict__ HL) {
    int tid = blockIdx.x * 256 + threadIdx.x;  // 4*1024*16 = 65536
    int n = tid & (kNS - 1);
    int d = (tid >> 4) & (kDI - 1);
    int g = tid >> 14;  // dir*2 + b
    int sid = (g << 10) + d;
    float h = 0.f;
    for (int c = 0; c < kCH; ++c) {
        size_t idx = ((size_t)sid * kCH + c) * kNS + n;
        float pav = PA[idx], hlv = HL[idx];
        PA[idx] = h;  // HIN for chunk c
        h = pav * h + hlv;
    }
}

__global__ __launch_bounds__(256) void scan_phase3(const bf16* __restrict__ xc,
                                                   const bf16* __restrict__ xdbl,
                                                   const bf16* __restrict__ xz,
                                                   const bf16* __restrict__ wdt,
                                                   const void* __restrict__ dtb_f,
                                                   const void* __restrict__ dtb_b,
                                                   const void* __restrict__ alog_f,
                                                   const void* __restrict__ alog_b,
                                                   const void* __restrict__ dp_f,
                                                   const void* __restrict__ dp_b,
                                                   const float* __restrict__ HIN,
                                                   bf16* __restrict__ ymul,
                                                   const int* __restrict__ flg) {
    int f32 = *flg;
    int tid = blockIdx.x * 256 + threadIdx.x;
    int d   = tid & (kDI - 1);
    int c   = (tid >> 10) & (kCH - 1);
    int b   = (tid >> 14) & 1;
    int dir = tid >> 15;
    const void* alog = dir ? alog_b : alog_f;
    float dtb_v = ldin(dir ? dtb_b : dtb_f, d, f32);
    float Dv = ldin(dir ? dp_b : dp_f, d, f32);
    float wreg[kDTR];
    const bf16* wrow = wdt + ((size_t)dir * kDI + d) * kDTR;
#pragma unroll
    for (int k = 0; k < kDTR; ++k) wreg[k] = toF(wrow[k]);
    int sid = ((dir * kB + b) << 10) + d;
    size_t o = ((size_t)sid * kCH + c) * kNS;
    float an[kNS], h[kNS];
#pragma unroll
    for (int n = 0; n < kNS; ++n) {
        an[n] = -__expf(ldin(alog, d * kNS + n, f32));
        h[n] = HIN[o + n];
    }
    int l0 = c * kCL;
    for (int l = l0; l < l0 + kCL; ++l) {
        size_t rb = (size_t)b * kL + l;
        const bf16* xrow = xdbl + rb * 128 + dir * 64;
        float accd = dtb_v;
#pragma unroll
        for (int k = 0; k < kDTR; ++k) accd += toF(xrow[k]) * wreg[k];
        float dl = (accd > 20.f) ? accd : log1pf(__expf(accd));
        float xcv = toF(xc[rb * (2 * kDI) + dir * kDI + d]);
        float du = dl * xcv;
        const bf16* Bp = xrow + kDTR;
        const bf16* Cp = xrow + kDTR + kNS;
        float y = 0.f;
#pragma unroll
        for (int n = 0; n < kNS; ++n) {
            float a = __expf(dl * an[n]);
            h[n] = a * h[n] + du * toF(Bp[n]);
            y += h[n] * toF(Cp[n]);
        }
        y += xcv * Dv;
        float zv = toF(xz[rb * (4 * kDI) + dir * 2048 + kDI + d]);
        float sz = zv / (1.f + __expf(-zv));
        ymul[rb * (2 * kDI) + dir * kDI + d] = __float2bfloat16(y * sz);
    }
}

// ---------------- cluster-center norms ----------------
__global__ void cnorm_kernel(const void* __restrict__ C, float* __restrict__ cn,
                             const int* __restrict__ flg) {
    int f32 = *flg;
    int c = blockIdx.x;
    int lane = threadIdx.x;  // 64 threads
    float s = 0.f;
    for (int i = lane; i < kD; i += 64) {
        float v = ldin(C, c * kD + i, f32);
        s += v * v;
    }
#pragma unroll
    for (int o = 32; o > 0; o >>= 1) s += __shfl_down(s, o, 64);
    if (lane == 0) cn[c] = sqrtf(s);
}

// ---------------- context clustering ----------------
__global__ __launch_bounds__(256) void cc_kernel(const bf16* __restrict__ proj,
                                                 const void* __restrict__ centers,
                                                 const float* __restrict__ cn,
                                                 const bf16* __restrict__ xn,
                                                 const void* __restrict__ alpha_p,
                                                 const void* __restrict__ g,
                                                 const void* __restrict__ bb,
                                                 bf16* __restrict__ ccout,
                                                 const int* __restrict__ flg) {
    __shared__ float sred[8];
    __shared__ float sims[kNC];
    int f32 = *flg;
    int row = blockIdx.x;
    int i = threadIdx.x;
    size_t base = (size_t)row * kD;
    float p0 = toF(proj[base + i]), p1 = toF(proj[base + i + 256]);
    float sumsq = blockReduceSum(p0 * p0 + p1 * p1, sred);
    float pn = fmaxf(sqrtf(sumsq), 1e-12f);
    for (int c = 0; c < kNC; ++c) {
        float part = p0 * ldin(centers, c * kD + i, f32) + p1 * ldin(centers, c * kD + i + 256, f32);
        float dot = blockReduceSum(part, sred);
        if (threadIdx.x == 0) sims[c] = dot / (pn * fmaxf(cn[c], 1e-12f));
    }
    __syncthreads();
    float mx = -1e30f;
#pragma unroll
    for (int c = 0; c < kNC; ++c) mx = fmaxf(mx, sims[c]);
    float wv[kNC], se = 0.f;
#pragma unroll
    for (int c = 0; c < kNC; ++c) { wv[c] = __expf(sims[c] - mx); se += wv[c]; }
    float inv = 1.f / se;
    float ctx0 = 0.f, ctx1 = 0.f;
#pragma unroll
    for (int c = 0; c < kNC; ++c) {
        float wc = wv[c] * inv;
        ctx0 += wc * ldin(centers, c * kD + i, f32);
        ctx1 += wc * ldin(centers, c * kD + i + 256, f32);
    }
    float alpha = ldin(alpha_p, 0, f32);
    float t0 = toF(xn[base + i]) + alpha * ctx0;
    float t1 = toF(xn[base + i + 256]) + alpha * ctx1;
    float mean = blockReduceSum(t0 + t1, sred) * (1.f / kD);
    float vs = blockReduceSum(t0 * t0 + t1 * t1, sred) * (1.f / kD) - mean * mean;
    float rstd = rsqrtf(vs + kEPS);
    ccout[base + i]       = __float2bfloat16((t0 - mean) * rstd * ldin(g, i, f32)       + ldin(bb, i, f32));
    ccout[base + i + 256] = __float2bfloat16((t1 - mean) * rstd * ldin(g, i + 256, f32) + ldin(bb, i + 256, f32));
}

// ---------------- gated fusion + residual -> fp32 xmid ----------------
__global__ __launch_bounds__(256) void gate_kernel(const bf16* __restrict__ xn,
                                                   const void* __restrict__ X,
                                                   const bf16* __restrict__ mo,
                                                   const bf16* __restrict__ cc,
                                                   const void* __restrict__ gw,
                                                   const void* __restrict__ gb,
                                                   float* __restrict__ xmid,
                                                   const int* __restrict__ flg) {
    __shared__ float sred[8];
    int f32 = *flg;
    int row = blockIdx.x;
    int i = threadIdx.x;
    size_t base = (size_t)row * kD;
    float x0 = toF(xn[base + i]), x1 = toF(xn[base + i + 256]);
    float d0 = blockReduceSum(x0 * ldin(gw, i, f32) + x1 * ldin(gw, i + 256, f32), sred);
    float d1 = blockReduceSum(x0 * ldin(gw, kD + i, f32) + x1 * ldin(gw, kD + i + 256, f32), sred);
    d0 += ldin(gb, 0, f32);
    d1 += ldin(gb, 1, f32);
    float mx = fmaxf(d0, d1);
    float e0 = __expf(d0 - mx), e1 = __expf(d1 - mx);
    float s = e0 + e1;
    float g0 = e0 / s, g1 = e1 / s;
    xmid[base + i]       = ldin(X, base + i, f32)       + g0 * toF(mo[base + i])       + g1 * toF(cc[base + i]);
    xmid[base + i + 256] = ldin(X, base + i + 256, f32) + g0 * toF(mo[base + i + 256]) + g1 * toF(cc[base + i + 256]);
}

// ---------------- launch ----------------
extern "C" void kernel_launch(void* const* d_in, const int* in_sizes, int n_in,
                              void* d_out, int out_size, void* d_ws, size_t ws_size,
                              hipStream_t stream) {
    bool sig = (n_in > 3 && in_sizes[3] == 2 * kDI * kD);
    int I_fusion_w = sig ? 21 : 3,  I_fusion_b = sig ? 22 : 4;
    int I_centers  = sig ? 23 : 5,  I_ccp_w    = sig ? 24 : 6,  I_ccp_b = sig ? 25 : 7;
    int I_ccn_g    = sig ? 26 : 8,  I_ccn_b    = sig ? 27 : 9,  I_alpha = sig ? 28 : 10;
    int I_gate_w   = sig ? 29 : 11, I_gate_b   = sig ? 30 : 12;
    int I_ffn_g    = sig ? 31 : 13, I_ffn_b    = sig ? 32 : 14;
    int I_ffn_w1   = sig ? 33 : 15, I_ffn_b1   = sig ? 34 : 16;
    int I_ffn_w2   = sig ? 35 : 17, I_ffn_b2   = sig ? 36 : 18;
    int I_fm       = sig ? 3  : 19, I_bm       = sig ? 12 : 28;

    const void* X        = d_in[0];
    const void* n1g      = d_in[1];
    const void* n1b      = d_in[2];
    const void* fusion_b = d_in[I_fusion_b];
    const void* centers  = d_in[I_centers];
    const void* ccp_b    = d_in[I_ccp_b];
    const void* ccn_g    = d_in[I_ccn_g];
    const void* ccn_b    = d_in[I_ccn_b];
    const void* cc_alpha = d_in[I_alpha];
    const void* gate_w   = d_in[I_gate_w];
    const void* gate_b   = d_in[I_gate_b];
    const void* ffn_g    = d_in[I_ffn_g];
    const void* ffn_b    = d_in[I_ffn_b];
    const void* ffn_b1   = d_in[I_ffn_b1];
    const void* ffn_b2   = d_in[I_ffn_b2];

    // ---- workspace layout (FLOAT units; bf16 counts halved) — total 61.2 MB ----
    float* ws = (float*)d_ws;
    int* flg  = (int*)d_ws;           // ws[0]
    float* cn = ws + 8;               // 8 floats
    float* PA   = ws + 32;                          // 1,048,576 f32
    float* HL   = PA + 1048576;                     // 1,048,576 f32
    bf16*  xn   = (bf16*)(HL + 1048576);            // 1,048,576 bf16 = 524,288 f
    bf16*  xz   = (bf16*)((float*)xn + 524288);     // 2048x4096 bf16 = 4,194,304 f
    bf16*  xc   = (bf16*)((float*)xz + 4194304);    // 2048x2048 bf16 = 2,097,152 f
    bf16*  xdbl = (bf16*)((float*)xc + 2097152);    // 2048x128 bf16 = 131,072 f
    bf16*  ymul = (bf16*)((float*)xdbl + 131072);   // 2048x2048 bf16 = 2,097,152 f
    bf16*  fb   = (bf16*)((float*)ymul + 2097152);  // 2048x1024 bf16 = 1,048,576 f
    bf16*  wbuf = (bf16*)((float*)fb + 1048576);    // 6,225,920 bf16 = 3,112,960 f
    // aliases of dead regions (size-checked):
    bf16*  mo    = (bf16*)PA;   // after scan3 (1,048,576 bf16 <= PA region)
    float* xmid  = HL;          // after scan2 (exact fit)
    bf16*  hln   = xc;          // after scan3
    bf16*  ffnh  = xz;          // after scan3 (2048x2048 bf16 <= xz region)
    bf16*  ccout = ymul;        // after out_proj
    bf16*  projb = fb;          // after fusion GEMM

    // weight views (order: fm_in, bm_in, fm_xproj, bm_xproj, fm_dt, bm_dt, fm_out, bm_out, fusion, ccp, ffn1, ffn2)
    bf16* w_in     = wbuf + 0;        // [fm|bm] concat, N=4096 x K=512
    bf16* w_xp     = wbuf + 2097152;  // 2 x (64 x 1024)
    bf16* w_dt     = wbuf + 2228224;  // 2 x (1024 x 32)
    bf16* w_out    = wbuf + 2293760;  // 2 x (512 x 1024)
    bf16* w_fusion = wbuf + 3342336;
    bf16* w_ccp    = wbuf + 3866624;
    bf16* w_ffn1   = wbuf + 4128768;
    bf16* w_ffn2   = wbuf + 5177344;

    dim3 blk(256);
    constexpr int NOFLIP = 1 << 30;

    detect_kernel<<<1, 64, 0, stream>>>((const unsigned short*)X, flg);

    WSrcs srcs;
    srcs.p[0] = d_in[I_fm + 0]; srcs.p[1] = d_in[I_bm + 0];
    srcs.p[2] = d_in[I_fm + 3]; srcs.p[3] = d_in[I_bm + 3];
    srcs.p[4] = d_in[I_fm + 4]; srcs.p[5] = d_in[I_bm + 4];
    srcs.p[6] = d_in[I_fm + 8]; srcs.p[7] = d_in[I_bm + 8];
    srcs.p[8] = d_in[I_fusion_w]; srcs.p[9] = d_in[I_ccp_w];
    srcs.p[10] = d_in[I_ffn_w1]; srcs.p[11] = d_in[I_ffn_w2];
    wconv_kernel<<<dim3(512, 12), blk, 0, stream>>>(srcs, wbuf, flg);

    ln_in_kernel<<<kM, blk, 0, stream>>>(X, n1g, n1b, xn, flg);

    // in_proj both dirs: xn @ [w_fm_in|w_bm_in]^T, bm half written row-flipped
    mfma_gemm<128, 128, 2, 2><<<dim3(32, 16, 1), blk, 0, stream>>>(
        xn, kD, 0, w_in, kD, 0, nullptr, 0, nullptr, xz, nullptr, 4 * kDI, 0, 2048, 0, flg);

    // conv both dirs
    conv_kernel<<<2 * kM * kDI / 256, blk, 0, stream>>>(
        xz, d_in[I_fm + 1], d_in[I_fm + 2], d_in[I_bm + 1], d_in[I_bm + 2], xc, flg);

    // xproj both dirs: z-batched (N=64, K=1024)
    mfma_gemm<64, 64, 2, 2><<<dim3(1, 32, 2), blk, 0, stream>>>(
        xc, 2 * kDI, kDI, w_xp, kDI, 65536, nullptr, 0, nullptr, xdbl, nullptr, 128, 64,
        NOFLIP, 0, flg);

    // scan (delta inline)
    scan_phase1<<<256, blk, 0, stream>>>(xc, xdbl, w_dt, d_in[I_fm + 5], d_in[I_bm + 5],
                                         d_in[I_fm + 6], d_in[I_bm + 6], PA, HL, flg);
    scan_phase2<<<256, blk, 0, stream>>>(PA, HL);
    scan_phase3<<<256, blk, 0, stream>>>(xc, xdbl, xz, w_dt, d_in[I_fm + 5], d_in[I_bm + 5],
                                         d_in[I_fm + 6], d_in[I_bm + 6], d_in[I_fm + 7],
                                         d_in[I_bm + 7], PA, ymul, flg);

    // out_proj both dirs: z-batched; z=1 (bm) rows flipped back
    mfma_gemm<64, 64, 2, 2><<<dim3(8, 32, 2), blk, 0, stream>>>(
        ymul, 2 * kDI, kDI, w_out, kDI, 524288, nullptr, 0, nullptr, fb, nullptr, 2 * kD, kD,
        NOFLIP, 1, flg);

    // mamba_out = fb @ fusion_w^T + fusion_b
    mfma_gemm<64, 64, 2, 2><<<dim3(8, 32, 1), blk, 0, stream>>>(
        fb, 2 * kD, 0, w_fusion, 2 * kD, 0, fusion_b, 0, nullptr, mo, nullptr, kD, 0,
        NOFLIP, 0, flg);

    // proj = xn @ ccp_w^T + ccp_b  (into fb region, dead after fusion)
    mfma_gemm<64, 64, 2, 2><<<dim3(8, 32, 1), blk, 0, stream>>>(
        xn, kD, 0, w_ccp, kD, 0, ccp_b, 0, nullptr, projb, nullptr, kD, 0, NOFLIP, 0, flg);
    cnorm_kernel<<<kNC, 64, 0, stream>>>(centers, cn, flg);
    cc_kernel<<<kM, blk, 0, stream>>>(projb, centers, cn, xn, cc_alpha, ccn_g, ccn_b, ccout, flg);

    gate_kernel<<<kM, blk, 0, stream>>>(xn, X, mo, ccout, gate_w, gate_b, xmid, flg);

    // FFN
    ln_f32_kernel<<<kM, blk, 0, stream>>>(xmid, ffn_g, ffn_b, hln, flg);
    mfma_gemm<128, 64, 2, 2><<<dim3(32, 16, 1), blk, 0, stream>>>(
        hln, kD, 0, w_ffn1, kD, 0, ffn_b1, 2, nullptr, ffnh, nullptr, 4 * kD, 0, NOFLIP, 0, flg);
    mfma_gemm<64, 64, 2, 2><<<dim3(8, 32, 1), blk, 0, stream>>>(
        ffnh, 4 * kD, 0, w_ffn2, 4 * kD, 0, ffn_b2, 0, xmid, nullptr, d_out, kD, 0,
        NOFLIP, 0, flg);
}